// Round 1
// 364.178 us; speedup vs baseline: 1.0217x; 1.0217x over previous
//
#include <hip/hip_runtime.h>
#include <math.h>

#define NN 100000
#define NE 1600000
#define IN_DIM 256
#define HD 128           // HEADS*OUT_DIM
#define NEG_SLOPE 0.2f
#define SCAN_CHUNK 2048
#define NB_SCAN ((NN + SCAN_CHUNK - 1) / SCAN_CHUNK)   // 49

typedef __attribute__((ext_vector_type(8))) __bf16 bf16x8;
typedef __attribute__((ext_vector_type(4))) float floatx4;

__device__ inline unsigned short f2bf(float f) {
    unsigned int b = __float_as_uint(f);
    b += 0x7fffu + ((b >> 16) & 1u);   // round-to-nearest-even
    return (unsigned short)(b >> 16);
}
__device__ inline unsigned int pk(float lo, float hi) {
    return (unsigned int)f2bf(lo) | ((unsigned int)f2bf(hi) << 16);
}
__device__ inline float bflo(unsigned int u) { return __uint_as_float(u << 16); }
__device__ inline float bfhi(unsigned int u) { return __uint_as_float(u & 0xffff0000u); }
__device__ inline float lrelu(float v) { return (v > 0.f) ? v : v * NEG_SLOPE; }

// ---- prep: swizzle W[256][128] fp32 -> bf16 B-fragments for 16x16x32 MFMA ----
// frag f = (c*8+t)*64+lane holds B[k=c*32+(lane>>4)*8+j][n=t*16+(lane&15)], j=0..7
__global__ __launch_bounds__(256) void prep_w_kernel(const float* __restrict__ W,
                                                     unsigned int* __restrict__ wswz) {
    int g = blockIdx.x * 256 + threadIdx.x;   // 0..4095
    int lane = g & 63;
    int t = (g >> 6) & 7;
    int c = g >> 9;
    int sub = lane & 15, quad = lane >> 4;
    int n = t * 16 + sub;
    int kbase = c * 32 + quad * 8;
    unsigned int ob = (unsigned int)g * 4;
#pragma unroll
    for (int i = 0; i < 4; ++i) {
        float lo = W[(size_t)(kbase + 2 * i) * HD + n];
        float hi = W[(size_t)(kbase + 2 * i + 1) * HD + n];
        wswz[ob + i] = pk(lo, hi);
    }
}

// ---- GEMM (MFMA, NO LDS): feat_bf16 = bf16(x @ W), el/er fused ----
// One wave = 16 rows (1 m-tile). Grid = 1563 blocks -> 6250 waves (~6/SIMD
// grid-wise); __launch_bounds__(256,4) pins VGPR<=128 so 4 waves/SIMD are
// resident. All A loads for the full K are issued up front (16 dwordx4 in
// flight -> HBM latency paid once per wave); the chunk loop then only waits
// on L2-resident wswz reads, covered by the other 3 waves' MFMA issue.
// feat layout: shorts [row][sub*8 + t]  (t = n-tile, sub = col-within-tile)
__global__ __launch_bounds__(256, 4) void gemm_kernel(const float* __restrict__ x,
                                                      const uint4* __restrict__ wswz,
                                                      const float* __restrict__ attn_l,
                                                      const float* __restrict__ attn_r,
                                                      unsigned short* __restrict__ featb,
                                                      float* __restrict__ el,
                                                      float* __restrict__ er) {
    const int tid = threadIdx.x;
    const int lane = tid & 63, wv = tid >> 6;
    const int sub = lane & 15, quad = lane >> 4;
    const int row0 = blockIdx.x * 64 + wv * 16;  // wave covers rows row0..row0+15

    int m = row0 + sub;
    if (m >= NN) m = NN - 1;                     // clamp loads; stores guarded
    const float* xp = x + (size_t)m * IN_DIM + quad * 8;

    // Preload + convert the full A row-fragment (two halves bound reg pressure)
    bf16x8 af[8];
#pragma unroll
    for (int h = 0; h < 2; ++h) {
        float4 raw[4][2];
#pragma unroll
        for (int c = 0; c < 4; ++c) {
            raw[c][0] = *(const float4*)(xp + (h * 4 + c) * 32);
            raw[c][1] = *(const float4*)(xp + (h * 4 + c) * 32 + 4);
        }
#pragma unroll
        for (int c = 0; c < 4; ++c) {
            uint4 au;
            au.x = pk(raw[c][0].x, raw[c][0].y);
            au.y = pk(raw[c][0].z, raw[c][0].w);
            au.z = pk(raw[c][1].x, raw[c][1].y);
            au.w = pk(raw[c][1].z, raw[c][1].w);
            af[h * 4 + c] = __builtin_bit_cast(bf16x8, au);
        }
    }

    floatx4 acc[8];
#pragma unroll
    for (int t = 0; t < 8; ++t) acc[t] = (floatx4){0.f, 0.f, 0.f, 0.f};

#pragma unroll
    for (int c = 0; c < 8; ++c) {
        uint4 bu[8];
#pragma unroll
        for (int t = 0; t < 8; ++t) bu[t] = wswz[(c * 8 + t) * 64 + lane];
#pragma unroll
        for (int t = 0; t < 8; ++t) {
            bf16x8 bfr = __builtin_bit_cast(bf16x8, bu[t]);
            acc[t] = __builtin_amdgcn_mfma_f32_16x16x32_bf16(af[c], bfr, acc[t], 0, 0, 0);
        }
    }

    // attn vectors: col = t*16+sub -> flat idx = t*16+sub
    float al[8], ar[8];
#pragma unroll
    for (int t = 0; t < 8; ++t) {
        al[t] = attn_l[t * 16 + sub];
        ar[t] = attn_r[t * 16 + sub];
    }

#pragma unroll
    for (int r = 0; r < 4; ++r) {
        int row = row0 + quad * 4 + r;           // C/D: row = quad*4 + reg
        uint4 fv;
        fv.x = pk(acc[0][r], acc[1][r]);
        fv.y = pk(acc[2][r], acc[3][r]);
        fv.z = pk(acc[4][r], acc[5][r]);
        fv.w = pk(acc[6][r], acc[7][r]);
        float pl[4], pr[4];
#pragma unroll
        for (int hh = 0; hh < 4; ++hh) {
            pl[hh] = acc[2 * hh][r] * al[2 * hh] + acc[2 * hh + 1][r] * al[2 * hh + 1];
            pr[hh] = acc[2 * hh][r] * ar[2 * hh] + acc[2 * hh + 1][r] * ar[2 * hh + 1];
        }
#pragma unroll
        for (int o = 1; o < 16; o <<= 1) {
#pragma unroll
            for (int hh = 0; hh < 4; ++hh) {
                pl[hh] += __shfl_xor(pl[hh], o);
                pr[hh] += __shfl_xor(pr[hh], o);
            }
        }
        if (row < NN) {
            *(uint4*)(featb + (size_t)row * HD + sub * 8) = fv;
            if (sub < 4) {
                float vl = (sub == 0) ? pl[0] : (sub == 1) ? pl[1] : (sub == 2) ? pl[2] : pl[3];
                float vr = (sub == 0) ? pr[0] : (sub == 1) ? pr[1] : (sub == 2) ? pr[2] : pr[3];
                el[row * 4 + sub] = vl;
                er[row * 4 + sub] = vr;
            }
        }
    }
}

// ---- degree histogram + rank (8 edges/thread, coalesced rank write) ----
__global__ __launch_bounds__(256) void hist_kernel(const int4* __restrict__ dst4,
                                                   int* __restrict__ deg,
                                                   int4* __restrict__ rank4) {
    int t = blockIdx.x * 256 + threadIdx.x;     // group of 8 edges
    if (t >= NE / 8) return;
    int4 d0 = dst4[t * 2];
    int4 d1 = dst4[t * 2 + 1];
    int4 r0, r1;
    r0.x = atomicAdd(&deg[d0.x], 1);
    r0.y = atomicAdd(&deg[d0.y], 1);
    r0.z = atomicAdd(&deg[d0.z], 1);
    r0.w = atomicAdd(&deg[d0.w], 1);
    r1.x = atomicAdd(&deg[d1.x], 1);
    r1.y = atomicAdd(&deg[d1.y], 1);
    r1.z = atomicAdd(&deg[d1.z], 1);
    r1.w = atomicAdd(&deg[d1.w], 1);
    rank4[t * 2]     = r0;
    rank4[t * 2 + 1] = r1;
}

// ---------------- exclusive scan (3 kernels) ----------------
__global__ __launch_bounds__(256) void scan1_kernel(const int* __restrict__ deg,
                                                    int* __restrict__ offs,
                                                    int* __restrict__ bsum) {
    __shared__ int sh[256];
    int b = blockIdx.x, t = threadIdx.x;
    int base = b * SCAN_CHUNK + t * 8;
    int v[8];
    int s = 0;
#pragma unroll
    for (int j = 0; j < 8; ++j) {
        int i = base + j;
        v[j] = (i < NN) ? deg[i] : 0;
        s += v[j];
    }
    sh[t] = s;
    __syncthreads();
    for (int o = 1; o < 256; o <<= 1) {
        int add = (t >= o) ? sh[t - o] : 0;
        __syncthreads();
        sh[t] += add;
        __syncthreads();
    }
    int incl = sh[t];
    int run = incl - s;
#pragma unroll
    for (int j = 0; j < 8; ++j) {
        int i = base + j;
        if (i < NN) offs[i] = run;
        run += v[j];
    }
    if (t == 255) bsum[b] = incl;
}

__global__ void scan2_kernel(int* __restrict__ bsum, int* __restrict__ offs) {
    int t = threadIdx.x;
    int x = (t < NB_SCAN) ? bsum[t] : 0;
    int v = x;
#pragma unroll
    for (int o = 1; o < 64; o <<= 1) {
        int u = __shfl_up(v, o);
        if (t >= o) v += u;
    }
    if (t < NB_SCAN) bsum[t] = v - x;
    if (t == NB_SCAN - 1) offs[NN] = v;
}

__global__ __launch_bounds__(256) void scan3_kernel(int* __restrict__ offs,
                                                    const int* __restrict__ bsum) {
    int b = blockIdx.x;
    int add = bsum[b];
    if (add == 0) return;
    int base = b * SCAN_CHUNK + threadIdx.x * 8;
#pragma unroll
    for (int j = 0; j < 8; ++j) {
        int i = base + j;
        if (i < NN) offs[i] += add;
    }
}

// ---- CSR fill: no atomics, 8 edges/thread, independent scatters ----
__global__ __launch_bounds__(256) void fill_csr_kernel(const int4* __restrict__ src4,
                                                       const int4* __restrict__ dst4,
                                                       const int4* __restrict__ rank4,
                                                       const int* __restrict__ offs,
                                                       int* __restrict__ csr_src) {
    int t = blockIdx.x * 256 + threadIdx.x;     // group of 8 edges
    if (t >= NE / 8) return;
    int4 d0 = dst4[t * 2],     d1 = dst4[t * 2 + 1];
    int4 r0 = rank4[t * 2],    r1 = rank4[t * 2 + 1];
    int4 s0 = src4[t * 2],     s1 = src4[t * 2 + 1];
    csr_src[offs[d0.x] + r0.x] = s0.x;
    csr_src[offs[d0.y] + r0.y] = s0.y;
    csr_src[offs[d0.z] + r0.z] = s0.z;
    csr_src[offs[d0.w] + r0.w] = s0.w;
    csr_src[offs[d1.x] + r1.x] = s1.x;
    csr_src[offs[d1.y] + r1.y] = s1.y;
    csr_src[offs[d1.z] + r1.z] = s1.z;
    csr_src[offs[d1.w] + r1.w] = s1.w;
}

// ---------------- softmax + aggregation (single pass) ----------------
// one wave = 4 nodes; 16 lanes per node. lane sub owns cols (d=sub, d=16+sub)
// of all 4 heads: uint4 at featu4[s*16+sub] = {h0,h1,h2,h3}, lo16=d=sub, hi16=d=16+sub.
#define CH 32
__global__ __launch_bounds__(256) void aggregate_kernel(const uint4* __restrict__ featu4,
                                                        const float4* __restrict__ el4,
                                                        const float4* __restrict__ er4,
                                                        const int* __restrict__ offs,
                                                        const int* __restrict__ csr_src,
                                                        float* __restrict__ out) {
    __shared__ int    s_sv[4][4][CH];
    __shared__ float4 s_a4[4][4][CH];

    const int tid = threadIdx.x;
    const int lane = tid & 63, wv = tid >> 6;
    const int g = lane >> 4, sub = lane & 15;
    const int node = blockIdx.x * 16 + wv * 4 + g;   // NN == 6250*16 exactly
    const int beg = offs[node], end = offs[node + 1];

    const float4 erv = er4[node];
    float4 sm = make_float4(0.f, 0.f, 0.f, 0.f);
    float acc[8];
#pragma unroll
    for (int i = 0; i < 8; ++i) acc[i] = 0.f;

    for (int c0 = beg; c0 < end; c0 += CH) {
        int cnt = end - c0;
        if (cnt > CH) cnt = CH;
        // stage weights: lane handles slots sub and sub+16
#pragma unroll
        for (int t = 0; t < 2; ++t) {
            int slot = sub + t * 16;
            if (slot < cnt) {
                int s = csr_src[c0 + slot];
                float4 e = el4[s];
                float4 w;
                w.x = __expf(lrelu(e.x + erv.x));
                w.y = __expf(lrelu(e.y + erv.y));
                w.z = __expf(lrelu(e.z + erv.z));
                w.w = __expf(lrelu(e.w + erv.w));
                sm.x += w.x; sm.y += w.y; sm.z += w.z; sm.w += w.w;
                s_sv[wv][g][slot] = s;
                s_a4[wv][g][slot] = w;
            }
        }
        // gather: unroll 4 for MLP (4 dwordx4 loads in flight)
        int j = 0;
        for (; j + 4 <= cnt; j += 4) {
            int s0 = s_sv[wv][g][j + 0];
            int s1 = s_sv[wv][g][j + 1];
            int s2 = s_sv[wv][g][j + 2];
            int s3 = s_sv[wv][g][j + 3];
            uint4 u0 = featu4[(size_t)s0 * 16 + sub];
            uint4 u1 = featu4[(size_t)s1 * 16 + sub];
            uint4 u2 = featu4[(size_t)s2 * 16 + sub];
            uint4 u3 = featu4[(size_t)s3 * 16 + sub];
            float4 w0 = s_a4[wv][g][j + 0];
            float4 w1 = s_a4[wv][g][j + 1];
            float4 w2 = s_a4[wv][g][j + 2];
            float4 w3 = s_a4[wv][g][j + 3];
            acc[0] = fmaf(w0.x, bflo(u0.x), acc[0]); acc[1] = fmaf(w0.x, bfhi(u0.x), acc[1]);
            acc[2] = fmaf(w0.y, bflo(u0.y), acc[2]); acc[3] = fmaf(w0.y, bfhi(u0.y), acc[3]);
            acc[4] = fmaf(w0.z, bflo(u0.z), acc[4]); acc[5] = fmaf(w0.z, bfhi(u0.z), acc[5]);
            acc[6] = fmaf(w0.w, bflo(u0.w), acc[6]); acc[7] = fmaf(w0.w, bfhi(u0.w), acc[7]);
            acc[0] = fmaf(w1.x, bflo(u1.x), acc[0]); acc[1] = fmaf(w1.x, bfhi(u1.x), acc[1]);
            acc[2] = fmaf(w1.y, bflo(u1.y), acc[2]); acc[3] = fmaf(w1.y, bfhi(u1.y), acc[3]);
            acc[4] = fmaf(w1.z, bflo(u1.z), acc[4]); acc[5] = fmaf(w1.z, bfhi(u1.z), acc[5]);
            acc[6] = fmaf(w1.w, bflo(u1.w), acc[6]); acc[7] = fmaf(w1.w, bfhi(u1.w), acc[7]);
            acc[0] = fmaf(w2.x, bflo(u2.x), acc[0]); acc[1] = fmaf(w2.x, bfhi(u2.x), acc[1]);
            acc[2] = fmaf(w2.y, bflo(u2.y), acc[2]); acc[3] = fmaf(w2.y, bfhi(u2.y), acc[3]);
            acc[4] = fmaf(w2.z, bflo(u2.z), acc[4]); acc[5] = fmaf(w2.z, bfhi(u2.z), acc[5]);
            acc[6] = fmaf(w2.w, bflo(u2.w), acc[6]); acc[7] = fmaf(w2.w, bfhi(u2.w), acc[7]);
            acc[0] = fmaf(w3.x, bflo(u3.x), acc[0]); acc[1] = fmaf(w3.x, bfhi(u3.x), acc[1]);
            acc[2] = fmaf(w3.y, bflo(u3.y), acc[2]); acc[3] = fmaf(w3.y, bfhi(u3.y), acc[3]);
            acc[4] = fmaf(w3.z, bflo(u3.z), acc[4]); acc[5] = fmaf(w3.z, bfhi(u3.z), acc[5]);
            acc[6] = fmaf(w3.w, bflo(u3.w), acc[6]); acc[7] = fmaf(w3.w, bfhi(u3.w), acc[7]);
        }
        for (; j < cnt; ++j) {
            int s = s_sv[wv][g][j];
            uint4 u = featu4[(size_t)s * 16 + sub];
            float4 w = s_a4[wv][g][j];
            acc[0] = fmaf(w.x, bflo(u.x), acc[0]); acc[1] = fmaf(w.x, bfhi(u.x), acc[1]);
            acc[2] = fmaf(w.y, bflo(u.y), acc[2]); acc[3] = fmaf(w.y, bfhi(u.y), acc[3]);
            acc[4] = fmaf(w.z, bflo(u.z), acc[4]); acc[5] = fmaf(w.z, bfhi(u.z), acc[5]);
            acc[6] = fmaf(w.w, bflo(u.w), acc[6]); acc[7] = fmaf(w.w, bfhi(u.w), acc[7]);
        }
    }

    // reduce denominators across the 16 lanes of this node
#pragma unroll
    for (int o = 1; o < 16; o <<= 1) {
        sm.x += __shfl_xor(sm.x, o);
        sm.y += __shfl_xor(sm.y, o);
        sm.z += __shfl_xor(sm.z, o);
        sm.w += __shfl_xor(sm.w, o);
    }
    float ix = 1.f / fmaxf(sm.x, 1e-9f);
    float iy = 1.f / fmaxf(sm.y, 1e-9f);
    float iz = 1.f / fmaxf(sm.z, 1e-9f);
    float iw = 1.f / fmaxf(sm.w, 1e-9f);
    float ox = 0.25f * (acc[0] * ix + acc[2] * iy + acc[4] * iz + acc[6] * iw);
    float oy = 0.25f * (acc[1] * ix + acc[3] * iy + acc[5] * iz + acc[7] * iw);
    out[node * 32 + sub]      = ox;
    out[node * 32 + 16 + sub] = oy;
}

// ---------------- launch ----------------
extern "C" void kernel_launch(void* const* d_in, const int* in_sizes, int n_in,
                              void* d_out, int out_size, void* d_ws, size_t ws_size,
                              hipStream_t stream) {
    const float* x      = (const float*)d_in[0];
    const float* W      = (const float*)d_in[1];
    const float* attn_l = (const float*)d_in[2];
    const float* attn_r = (const float*)d_in[3];
    const int*   src    = (const int*)d_in[4];
    const int*   dst    = (const int*)d_in[5];
    float* out = (float*)d_out;

    char* p = (char*)d_ws;
    auto alloc = [&](size_t bytes) -> void* {
        void* r = (void*)p;
        p += (bytes + 255) & ~(size_t)255;
        return r;
    };
    unsigned short* featb = (unsigned short*)alloc((size_t)NN * HD * 2);
    unsigned int*   wswz  = (unsigned int*)alloc(4096 * 16);
    float* el     = (float*)alloc((size_t)NN * 4 * 4);
    float* er     = (float*)alloc((size_t)NN * 4 * 4);
    int*   offs   = (int*)alloc((size_t)(NN + 1) * 4);
    int*   deg    = (int*)alloc((size_t)NN * 4);
    int*   rank   = (int*)alloc((size_t)NE * 4);
    int*   bsum   = (int*)alloc(64 * 4);
    int*   csr    = (int*)alloc((size_t)NE * 4);

    hipMemsetAsync(deg, 0, (size_t)NN * 4, stream);

    prep_w_kernel<<<16, 256, 0, stream>>>(W, wswz);
    gemm_kernel<<<(NN + 63) / 64, 256, 0, stream>>>(x, (const uint4*)wswz, attn_l, attn_r,
                                                    featb, el, er);
    hist_kernel<<<(NE / 8 + 255) / 256, 256, 0, stream>>>((const int4*)dst, deg, (int4*)rank);
    scan1_kernel<<<NB_SCAN, 256, 0, stream>>>(deg, offs, bsum);
    scan2_kernel<<<1, 64, 0, stream>>>(bsum, offs);
    scan3_kernel<<<NB_SCAN, 256, 0, stream>>>(offs, bsum);
    fill_csr_kernel<<<(NE / 8 + 255) / 256, 256, 0, stream>>>((const int4*)src, (const int4*)dst,
                                                              (const int4*)rank, offs, csr);
    aggregate_kernel<<<NN / 16, 256, 0, stream>>>((const uint4*)featb, (const float4*)el,
                                                  (const float4*)er, offs, csr, out);
}

// Round 2
// 303.592 us; speedup vs baseline: 1.2257x; 1.1996x over previous
//
#include <hip/hip_runtime.h>
#include <math.h>

#define NN 100000
#define NE 1600000
#define IN_DIM 256
#define HD 128           // HEADS*OUT_DIM
#define NEG_SLOPE 0.2f

#define B1SH 9                         // 512 nodes per coarse bucket
#define NPB (1 << B1SH)                // 512
#define NB1 ((NN + NPB - 1) / NPB)     // 196 coarse buckets
#define SC_BLOCKS ((NE / 4 + 1023) / 1024)   // 391 blocks, 4096 edges each

typedef __attribute__((ext_vector_type(8))) __bf16 bf16x8;
typedef __attribute__((ext_vector_type(4))) float floatx4;

__device__ inline unsigned short f2bf(float f) {
    unsigned int b = __float_as_uint(f);
    b += 0x7fffu + ((b >> 16) & 1u);   // round-to-nearest-even
    return (unsigned short)(b >> 16);
}
__device__ inline unsigned int pk(float lo, float hi) {
    return (unsigned int)f2bf(lo) | ((unsigned int)f2bf(hi) << 16);
}
__device__ inline float bflo(unsigned int u) { return __uint_as_float(u << 16); }
__device__ inline float bfhi(unsigned int u) { return __uint_as_float(u & 0xffff0000u); }
__device__ inline float lrelu(float v) { return (v > 0.f) ? v : v * NEG_SLOPE; }

// ---- prep: swizzle W[256][128] fp32 -> bf16 B-fragments for 16x16x32 MFMA ----
__global__ __launch_bounds__(256) void prep_w_kernel(const float* __restrict__ W,
                                                     unsigned int* __restrict__ wswz) {
    int g = blockIdx.x * 256 + threadIdx.x;   // 0..4095
    int lane = g & 63;
    int t = (g >> 6) & 7;
    int c = g >> 9;
    int sub = lane & 15, quad = lane >> 4;
    int n = t * 16 + sub;
    int kbase = c * 32 + quad * 8;
    unsigned int ob = (unsigned int)g * 4;
#pragma unroll
    for (int i = 0; i < 4; ++i) {
        float lo = W[(size_t)(kbase + 2 * i) * HD + n];
        float hi = W[(size_t)(kbase + 2 * i + 1) * HD + n];
        wswz[ob + i] = pk(lo, hi);
    }
}

// ---- GEMM (MFMA, NO LDS): feat_bf16 = bf16(x @ W), el/er fused ----
__global__ __launch_bounds__(256, 4) void gemm_kernel(const float* __restrict__ x,
                                                      const uint4* __restrict__ wswz,
                                                      const float* __restrict__ attn_l,
                                                      const float* __restrict__ attn_r,
                                                      unsigned short* __restrict__ featb,
                                                      float* __restrict__ el,
                                                      float* __restrict__ er) {
    const int tid = threadIdx.x;
    const int lane = tid & 63, wv = tid >> 6;
    const int sub = lane & 15, quad = lane >> 4;
    const int row0 = blockIdx.x * 64 + wv * 16;  // wave covers rows row0..row0+15

    int m = row0 + sub;
    if (m >= NN) m = NN - 1;                     // clamp loads; stores guarded
    const float* xp = x + (size_t)m * IN_DIM + quad * 8;

    bf16x8 af[8];
#pragma unroll
    for (int h = 0; h < 2; ++h) {
        float4 raw[4][2];
#pragma unroll
        for (int c = 0; c < 4; ++c) {
            raw[c][0] = *(const float4*)(xp + (h * 4 + c) * 32);
            raw[c][1] = *(const float4*)(xp + (h * 4 + c) * 32 + 4);
        }
#pragma unroll
        for (int c = 0; c < 4; ++c) {
            uint4 au;
            au.x = pk(raw[c][0].x, raw[c][0].y);
            au.y = pk(raw[c][0].z, raw[c][0].w);
            au.z = pk(raw[c][1].x, raw[c][1].y);
            au.w = pk(raw[c][1].z, raw[c][1].w);
            af[h * 4 + c] = __builtin_bit_cast(bf16x8, au);
        }
    }

    floatx4 acc[8];
#pragma unroll
    for (int t = 0; t < 8; ++t) acc[t] = (floatx4){0.f, 0.f, 0.f, 0.f};

#pragma unroll
    for (int c = 0; c < 8; ++c) {
        uint4 bu[8];
#pragma unroll
        for (int t = 0; t < 8; ++t) bu[t] = wswz[(c * 8 + t) * 64 + lane];
#pragma unroll
        for (int t = 0; t < 8; ++t) {
            bf16x8 bfr = __builtin_bit_cast(bf16x8, bu[t]);
            acc[t] = __builtin_amdgcn_mfma_f32_16x16x32_bf16(af[c], bfr, acc[t], 0, 0, 0);
        }
    }

    float al[8], ar[8];
#pragma unroll
    for (int t = 0; t < 8; ++t) {
        al[t] = attn_l[t * 16 + sub];
        ar[t] = attn_r[t * 16 + sub];
    }

#pragma unroll
    for (int r = 0; r < 4; ++r) {
        int row = row0 + quad * 4 + r;           // C/D: row = quad*4 + reg
        uint4 fv;
        fv.x = pk(acc[0][r], acc[1][r]);
        fv.y = pk(acc[2][r], acc[3][r]);
        fv.z = pk(acc[4][r], acc[5][r]);
        fv.w = pk(acc[6][r], acc[7][r]);
        float pl[4], pr[4];
#pragma unroll
        for (int hh = 0; hh < 4; ++hh) {
            pl[hh] = acc[2 * hh][r] * al[2 * hh] + acc[2 * hh + 1][r] * al[2 * hh + 1];
            pr[hh] = acc[2 * hh][r] * ar[2 * hh] + acc[2 * hh + 1][r] * ar[2 * hh + 1];
        }
#pragma unroll
        for (int o = 1; o < 16; o <<= 1) {
#pragma unroll
            for (int hh = 0; hh < 4; ++hh) {
                pl[hh] += __shfl_xor(pl[hh], o);
                pr[hh] += __shfl_xor(pr[hh], o);
            }
        }
        if (row < NN) {
            *(uint4*)(featb + (size_t)row * HD + sub * 8) = fv;
            if (sub < 4) {
                float vl = (sub == 0) ? pl[0] : (sub == 1) ? pl[1] : (sub == 2) ? pl[2] : pl[3];
                float vr = (sub == 0) ? pr[0] : (sub == 1) ? pr[1] : (sub == 2) ? pr[2] : pr[3];
                el[row * 4 + sub] = vl;
                er[row * 4 + sub] = vr;
            }
        }
    }
}

// ---- precount: per-block LDS histogram over 196 coarse buckets ----
__global__ __launch_bounds__(256) void precount_kernel(const int4* __restrict__ dst4,
                                                       int* __restrict__ gbcnt) {
    __shared__ int cnt[NB1];
    int t = threadIdx.x;
    for (int i = t; i < NB1; i += 256) cnt[i] = 0;
    __syncthreads();
    int base4 = blockIdx.x * 1024;
#pragma unroll
    for (int k = 0; k < 4; ++k) {
        int gi = base4 + k * 256 + t;
        if (gi < NE / 4) {
            int4 d = dst4[gi];
            atomicAdd(&cnt[d.x >> B1SH], 1);
            atomicAdd(&cnt[d.y >> B1SH], 1);
            atomicAdd(&cnt[d.z >> B1SH], 1);
            atomicAdd(&cnt[d.w >> B1SH], 1);
        }
    }
    __syncthreads();
    for (int i = t; i < NB1; i += 256)
        if (cnt[i]) atomicAdd(&gbcnt[i], cnt[i]);
}

// ---- bscan: exclusive scan over 196 bucket counts; init cursors; offs[NN] ----
__global__ __launch_bounds__(256) void bscan_kernel(const int* __restrict__ gbcnt,
                                                    int* __restrict__ regstart,
                                                    int* __restrict__ gcursor,
                                                    int* __restrict__ offs) {
    __shared__ int sh[256];
    int t = threadIdx.x;
    int v = (t < NB1) ? gbcnt[t] : 0;
    sh[t] = v;
    __syncthreads();
    for (int o = 1; o < 256; o <<= 1) {
        int a = (t >= o) ? sh[t - o] : 0;
        __syncthreads();
        sh[t] += a;
        __syncthreads();
    }
    int excl = sh[t] - v;
    if (t < NB1) {
        regstart[t] = excl;
        gcursor[t] = excl;
    }
    if (t == 0) {
        regstart[NB1] = NE;
        offs[NN] = NE;
    }
}

// ---- scatter: bucket edges into packed regions; one global atomic per
//      (block,bucket) reserves space; per-edge ranks via LDS atomics ----
__global__ __launch_bounds__(256) void scatter_kernel(const int4* __restrict__ src4,
                                                      const int4* __restrict__ dst4,
                                                      int* __restrict__ gcursor,
                                                      unsigned int* __restrict__ pkd) {
    __shared__ int cnt[NB1];
    __shared__ int gbase[NB1];
    int t = threadIdx.x;
    for (int i = t; i < NB1; i += 256) cnt[i] = 0;
    __syncthreads();

    int base4 = blockIdx.x * 1024;
    unsigned int pkv[16];
    unsigned int brk[16];
#pragma unroll
    for (int k = 0; k < 4; ++k) {
        int gi = base4 + k * 256 + t;
        bool ok = gi < NE / 4;
        int gic = ok ? gi : 0;
        int4 s = src4[gic];
        int4 d = dst4[gic];
        int dd[4] = {d.x, d.y, d.z, d.w};
        int ss[4] = {s.x, s.y, s.z, s.w};
#pragma unroll
        for (int j4 = 0; j4 < 4; ++j4) {
            int e = k * 4 + j4;
            if (ok) {
                int b = dd[j4] >> B1SH;
                int r = atomicAdd(&cnt[b], 1);                     // local rank
                brk[e] = ((unsigned int)b << 12) | (unsigned int)r; // r < 4096
                pkv[e] = ((unsigned int)(dd[j4] & (NPB - 1)) << 17) | (unsigned int)ss[j4];
            } else {
                brk[e] = 0xFFFFFFFFu;
            }
        }
    }
    __syncthreads();
    for (int i = t; i < NB1; i += 256)
        gbase[i] = cnt[i] ? atomicAdd(&gcursor[i], cnt[i]) : 0;
    __syncthreads();
#pragma unroll
    for (int e = 0; e < 16; ++e) {
        if (brk[e] != 0xFFFFFFFFu) {
            int b = brk[e] >> 12;
            int r = brk[e] & 0xFFF;
            pkd[gbase[b] + r] = pkv[e];
        }
    }
}

// ---- build: per-bucket fine histogram (= exact degrees), scan -> offs,
//      place csr_src via LDS cursors. One block per coarse bucket. ----
__global__ __launch_bounds__(256) void build_kernel(const unsigned int* __restrict__ pkd,
                                                    const int* __restrict__ regstart,
                                                    int* __restrict__ offs,
                                                    int* __restrict__ csr_src) {
    __shared__ int fcnt[NPB];
    __shared__ int foffs[NPB];
    __shared__ int ssc[256];
    int b = blockIdx.x, t = threadIdx.x;
    int rs = regstart[b], re = regstart[b + 1];
    int n = re - rs;

    for (int i = t; i < NPB; i += 256) fcnt[i] = 0;
    __syncthreads();
    for (int i = t; i < n; i += 256) {
        unsigned int v = pkd[rs + i];
        atomicAdd(&fcnt[v >> 17], 1);
    }
    __syncthreads();
    // exclusive scan of 512 counts (2 per thread)
    int a0 = fcnt[2 * t], a1 = fcnt[2 * t + 1];
    int s = a0 + a1;
    ssc[t] = s;
    __syncthreads();
    for (int o = 1; o < 256; o <<= 1) {
        int u = (t >= o) ? ssc[t - o] : 0;
        __syncthreads();
        ssc[t] += u;
        __syncthreads();
    }
    int excl = ssc[t] - s;
    foffs[2 * t] = excl;
    foffs[2 * t + 1] = excl + a0;
    __syncthreads();
#pragma unroll
    for (int q = 0; q < 2; ++q) {
        int j = t + q * 256;
        int node = b * NPB + j;
        if (node < NN) offs[node] = rs + foffs[j];
    }
    for (int i = t; i < NPB; i += 256) fcnt[i] = 0;   // reuse as cursors
    __syncthreads();
    // placement pass, 4x unrolled so loads overlap the LDS-atomic chains
    int i = t;
    for (; i + 768 < n; i += 1024) {
        unsigned int v0 = pkd[rs + i];
        unsigned int v1 = pkd[rs + i + 256];
        unsigned int v2 = pkd[rs + i + 512];
        unsigned int v3 = pkd[rs + i + 768];
        int j0 = v0 >> 17, j1 = v1 >> 17, j2 = v2 >> 17, j3 = v3 >> 17;
        int r0 = atomicAdd(&fcnt[j0], 1);
        int r1 = atomicAdd(&fcnt[j1], 1);
        int r2 = atomicAdd(&fcnt[j2], 1);
        int r3 = atomicAdd(&fcnt[j3], 1);
        csr_src[rs + foffs[j0] + r0] = (int)(v0 & 0x1FFFFu);
        csr_src[rs + foffs[j1] + r1] = (int)(v1 & 0x1FFFFu);
        csr_src[rs + foffs[j2] + r2] = (int)(v2 & 0x1FFFFu);
        csr_src[rs + foffs[j3] + r3] = (int)(v3 & 0x1FFFFu);
    }
    for (; i < n; i += 256) {
        unsigned int v = pkd[rs + i];
        int j = v >> 17;
        int r = atomicAdd(&fcnt[j], 1);
        csr_src[rs + foffs[j] + r] = (int)(v & 0x1FFFFu);
    }
}

// ---------------- softmax + aggregation (single pass) ----------------
#define CH 32
__global__ __launch_bounds__(256) void aggregate_kernel(const uint4* __restrict__ featu4,
                                                        const float4* __restrict__ el4,
                                                        const float4* __restrict__ er4,
                                                        const int* __restrict__ offs,
                                                        const int* __restrict__ csr_src,
                                                        float* __restrict__ out) {
    __shared__ int    s_sv[4][4][CH];
    __shared__ float4 s_a4[4][4][CH];

    const int tid = threadIdx.x;
    const int lane = tid & 63, wv = tid >> 6;
    const int g = lane >> 4, sub = lane & 15;
    const int node = blockIdx.x * 16 + wv * 4 + g;   // NN == 6250*16 exactly
    const int beg = offs[node], end = offs[node + 1];

    const float4 erv = er4[node];
    float4 sm = make_float4(0.f, 0.f, 0.f, 0.f);
    float acc[8];
#pragma unroll
    for (int i = 0; i < 8; ++i) acc[i] = 0.f;

    for (int c0 = beg; c0 < end; c0 += CH) {
        int cnt = end - c0;
        if (cnt > CH) cnt = CH;
#pragma unroll
        for (int t = 0; t < 2; ++t) {
            int slot = sub + t * 16;
            if (slot < cnt) {
                int s = csr_src[c0 + slot];
                float4 e = el4[s];
                float4 w;
                w.x = __expf(lrelu(e.x + erv.x));
                w.y = __expf(lrelu(e.y + erv.y));
                w.z = __expf(lrelu(e.z + erv.z));
                w.w = __expf(lrelu(e.w + erv.w));
                sm.x += w.x; sm.y += w.y; sm.z += w.z; sm.w += w.w;
                s_sv[wv][g][slot] = s;
                s_a4[wv][g][slot] = w;
            }
        }
        int j = 0;
        for (; j + 4 <= cnt; j += 4) {
            int s0 = s_sv[wv][g][j + 0];
            int s1 = s_sv[wv][g][j + 1];
            int s2 = s_sv[wv][g][j + 2];
            int s3 = s_sv[wv][g][j + 3];
            uint4 u0 = featu4[(size_t)s0 * 16 + sub];
            uint4 u1 = featu4[(size_t)s1 * 16 + sub];
            uint4 u2 = featu4[(size_t)s2 * 16 + sub];
            uint4 u3 = featu4[(size_t)s3 * 16 + sub];
            float4 w0 = s_a4[wv][g][j + 0];
            float4 w1 = s_a4[wv][g][j + 1];
            float4 w2 = s_a4[wv][g][j + 2];
            float4 w3 = s_a4[wv][g][j + 3];
            acc[0] = fmaf(w0.x, bflo(u0.x), acc[0]); acc[1] = fmaf(w0.x, bfhi(u0.x), acc[1]);
            acc[2] = fmaf(w0.y, bflo(u0.y), acc[2]); acc[3] = fmaf(w0.y, bfhi(u0.y), acc[3]);
            acc[4] = fmaf(w0.z, bflo(u0.z), acc[4]); acc[5] = fmaf(w0.z, bfhi(u0.z), acc[5]);
            acc[6] = fmaf(w0.w, bflo(u0.w), acc[6]); acc[7] = fmaf(w0.w, bfhi(u0.w), acc[7]);
            acc[0] = fmaf(w1.x, bflo(u1.x), acc[0]); acc[1] = fmaf(w1.x, bfhi(u1.x), acc[1]);
            acc[2] = fmaf(w1.y, bflo(u1.y), acc[2]); acc[3] = fmaf(w1.y, bfhi(u1.y), acc[3]);
            acc[4] = fmaf(w1.z, bflo(u1.z), acc[4]); acc[5] = fmaf(w1.z, bfhi(u1.z), acc[5]);
            acc[6] = fmaf(w1.w, bflo(u1.w), acc[6]); acc[7] = fmaf(w1.w, bfhi(u1.w), acc[7]);
            acc[0] = fmaf(w2.x, bflo(u2.x), acc[0]); acc[1] = fmaf(w2.x, bfhi(u2.x), acc[1]);
            acc[2] = fmaf(w2.y, bflo(u2.y), acc[2]); acc[3] = fmaf(w2.y, bfhi(u2.y), acc[3]);
            acc[4] = fmaf(w2.z, bflo(u2.z), acc[4]); acc[5] = fmaf(w2.z, bfhi(u2.z), acc[5]);
            acc[6] = fmaf(w2.w, bflo(u2.w), acc[6]); acc[7] = fmaf(w2.w, bfhi(u2.w), acc[7]);
            acc[0] = fmaf(w3.x, bflo(u3.x), acc[0]); acc[1] = fmaf(w3.x, bfhi(u3.x), acc[1]);
            acc[2] = fmaf(w3.y, bflo(u3.y), acc[2]); acc[3] = fmaf(w3.y, bfhi(u3.y), acc[3]);
            acc[4] = fmaf(w3.z, bflo(u3.z), acc[4]); acc[5] = fmaf(w3.z, bfhi(u3.z), acc[5]);
            acc[6] = fmaf(w3.w, bflo(u3.w), acc[6]); acc[7] = fmaf(w3.w, bfhi(u3.w), acc[7]);
        }
        for (; j < cnt; ++j) {
            int s = s_sv[wv][g][j];
            uint4 u = featu4[(size_t)s * 16 + sub];
            float4 w = s_a4[wv][g][j];
            acc[0] = fmaf(w.x, bflo(u.x), acc[0]); acc[1] = fmaf(w.x, bfhi(u.x), acc[1]);
            acc[2] = fmaf(w.y, bflo(u.y), acc[2]); acc[3] = fmaf(w.y, bfhi(u.y), acc[3]);
            acc[4] = fmaf(w.z, bflo(u.z), acc[4]); acc[5] = fmaf(w.z, bfhi(u.z), acc[5]);
            acc[6] = fmaf(w.w, bflo(u.w), acc[6]); acc[7] = fmaf(w.w, bfhi(u.w), acc[7]);
        }
    }

#pragma unroll
    for (int o = 1; o < 16; o <<= 1) {
        sm.x += __shfl_xor(sm.x, o);
        sm.y += __shfl_xor(sm.y, o);
        sm.z += __shfl_xor(sm.z, o);
        sm.w += __shfl_xor(sm.w, o);
    }
    float ix = 1.f / fmaxf(sm.x, 1e-9f);
    float iy = 1.f / fmaxf(sm.y, 1e-9f);
    float iz = 1.f / fmaxf(sm.z, 1e-9f);
    float iw = 1.f / fmaxf(sm.w, 1e-9f);
    float ox = 0.25f * (acc[0] * ix + acc[2] * iy + acc[4] * iz + acc[6] * iw);
    float oy = 0.25f * (acc[1] * ix + acc[3] * iy + acc[5] * iz + acc[7] * iw);
    out[node * 32 + sub]      = ox;
    out[node * 32 + 16 + sub] = oy;
}

// ---------------- launch ----------------
extern "C" void kernel_launch(void* const* d_in, const int* in_sizes, int n_in,
                              void* d_out, int out_size, void* d_ws, size_t ws_size,
                              hipStream_t stream) {
    const float* x      = (const float*)d_in[0];
    const float* W      = (const float*)d_in[1];
    const float* attn_l = (const float*)d_in[2];
    const float* attn_r = (const float*)d_in[3];
    const int*   src    = (const int*)d_in[4];
    const int*   dst    = (const int*)d_in[5];
    float* out = (float*)d_out;

    char* p = (char*)d_ws;
    auto alloc = [&](size_t bytes) -> void* {
        void* r = (void*)p;
        p += (bytes + 255) & ~(size_t)255;
        return r;
    };
    unsigned short* featb = (unsigned short*)alloc((size_t)NN * HD * 2);
    unsigned int*   wswz  = (unsigned int*)alloc(4096 * 16);
    float* el      = (float*)alloc((size_t)NN * 4 * 4);
    float* er      = (float*)alloc((size_t)NN * 4 * 4);
    int*   offs    = (int*)alloc((size_t)(NN + 1) * 4);
    unsigned int* pkd = (unsigned int*)alloc((size_t)NE * 4);
    int*   csr     = (int*)alloc((size_t)NE * 4);
    int*   gbcnt   = (int*)alloc((size_t)NB1 * 4);
    int*   regstart= (int*)alloc((size_t)(NB1 + 1) * 4);
    int*   gcursor = (int*)alloc((size_t)NB1 * 4);

    hipMemsetAsync(gbcnt, 0, (size_t)NB1 * 4, stream);

    prep_w_kernel<<<16, 256, 0, stream>>>(W, wswz);
    gemm_kernel<<<(NN + 63) / 64, 256, 0, stream>>>(x, (const uint4*)wswz, attn_l, attn_r,
                                                    featb, el, er);
    precount_kernel<<<SC_BLOCKS, 256, 0, stream>>>((const int4*)dst, gbcnt);
    bscan_kernel<<<1, 256, 0, stream>>>(gbcnt, regstart, gcursor, offs);
    scatter_kernel<<<SC_BLOCKS, 256, 0, stream>>>((const int4*)src, (const int4*)dst,
                                                  gcursor, pkd);
    build_kernel<<<NB1, 256, 0, stream>>>(pkd, regstart, offs, csr);
    aggregate_kernel<<<NN / 16, 256, 0, stream>>>((const uint4*)featb, (const float4*)el,
                                                  (const float4*)er, offs, csr, out);
}